// Round 6
// baseline (309.727 us; speedup 1.0000x reference)
//
#include <hip/hip_runtime.h>
#include <math.h>

typedef __bf16 bf16x8 __attribute__((ext_vector_type(8)));
typedef __bf16 bf16x4 __attribute__((ext_vector_type(4)));
typedef float  f32x4  __attribute__((ext_vector_type(4)));

// Problem constants
constexpr int B_  = 128;
constexpr int M_  = 512;
constexpr int L_  = 1024;
constexpr int H_  = 64;
constexpr int KL_ = 1536;

// Tiling: 64 query rows x 64 key cols; 4 waves = (2 row-halves a) x (2 col-halves c)
constexpr int BM = 64;
constexpr int KT = 64;
constexpr int NT = 17;               // 17*64 = 1088 covers the 1024-band + 64-row skew
constexpr int KS = 72;               // ks/vt row stride (bf16): 144B -> 2-way max on frag reads
constexpr int PPS = 192;             // ppos row stride (bf16): 3 rolling 64-wide chunks
constexpr int PSS = 40;              // ps row stride (bf16): 80B, 16B-aligned rows

// LDS layout — 53248 B total -> 3 blocks/CU (159744 <= 163840)
constexpr int OFF_KS   = 0;          // ks[64][72] bf16     9216 B (single buffer)
constexpr int OFF_VT   = 9216;       // vt[64][72] bf16     9216 B (V^T, single buffer)
constexpr int OFF_PPOS = 18432;      // ppos[64][192] bf16 24576 B (3 rolling QPE chunks)
constexpr int OFF_PS   = 43008;      // ps[4][32][40] bf16 10240 B (wave-private P)
constexpr int SMEM_BYTES = 53248;
// epilogue overlays (after final barrier):
constexpr int OFF_OBUF = 0;          // [2][64][36] f32 partial O (18432 B, over ks+vt)
constexpr int OFF_LSUM = 18432;      // [2][64] f32 row sums (over ppos, dead by then)
constexpr int OBS = 36;

// exp(x/8) == exp2(x * 0.125*log2(e)); fold into Q so QPE comes out pre-scaled too.
constexpr float QSCALE = 0.18033688011112043f;   // 0.125 * log2(e)

#define MFMA16(A, B, C) __builtin_amdgcn_mfma_f32_16x16x32_bf16((A), (B), (C), 0, 0, 0)

__global__ __launch_bounds__(256, 3)
void seqattn_v6(const float* __restrict__ Q, const float* __restrict__ K,
                const float* __restrict__ V, const float* __restrict__ PE,
                float* __restrict__ O) {
  __shared__ alignas(16) char smem[SMEM_BYTES];
  __bf16* ks   = (__bf16*)(smem + OFF_KS);
  __bf16* vt   = (__bf16*)(smem + OFF_VT);
  __bf16* ppos = (__bf16*)(smem + OFF_PPOS);

  const int tid  = threadIdx.x;
  const int w    = tid >> 6;
  const int lane = tid & 63;
  const int nid  = lane & 15;
  const int qid  = lane >> 4;
  const int a    = w >> 1;            // rows 32a..32a+31
  const int c    = w & 1;             // tile cols 32c..32c+31
  const int b    = blockIdx.x;        // batch on x -> same-batch blocks share an XCD
  const int m0   = blockIdx.y * BM;
  const int swz  = qid << 4;          // in-slot bank swizzle (slot width 64, xor bits 4..5)

  __bf16* ps = (__bf16*)(smem + OFF_PS) + w * 32 * PSS;

  // ---- Q A-fragments, pre-scaled by 0.125*log2(e) ----
  bf16x8 aq[2][2];
  #pragma unroll
  for (int it = 0; it < 2; ++it) {
    const float* qg = &Q[((size_t)b * M_ + m0 + 32 * a + 16 * it + nid) * H_];
    #pragma unroll
    for (int j = 0; j < 8; ++j) {
      aq[it][0][j] = (__bf16)(qg[8 * qid + j] * QSCALE);
      aq[it][1][j] = (__bf16)(qg[32 + 8 * qid + j] * QSCALE);
    }
  }

  f32x4 o[2][4];
  float lpart[2][4];
  #pragma unroll
  for (int it = 0; it < 2; ++it) {
    #pragma unroll
    for (int ht = 0; ht < 4; ++ht) o[it][ht] = (f32x4){0.f, 0.f, 0.f, 0.f};
    #pragma unroll
    for (int r = 0; r < 4; ++r) lpart[it][r] = 0.f;
  }

  const int krow = tid >> 2,  khq = (tid & 3) * 16;   // K staging: 4 thr/row
  const int vj = (tid & 15) * 4, vh = (tid >> 4) * 4; // V staging: 4x4 reg transpose

  // PE B-frag gather base: frag[nt][h][j] = PE[(32h+8qid+j)*L + ch*64+32c+16nt+nid]
  const float* peg = &PE[(size_t)(8 * qid) * L_ + 32 * c + nid];

  // ---------------- prologue: stage tile 0 + QPE chunk 0 (slot 0) ----------------
  {
    const float* kg = &K[((size_t)b * KL_ + m0 + krow) * H_ + khq];
    f32x4 k0 = *(const f32x4*)kg,       k1 = *(const f32x4*)(kg + 4);
    f32x4 k2 = *(const f32x4*)(kg + 8), k3 = *(const f32x4*)(kg + 12);
    const float* vg = &V[((size_t)b * KL_ + m0 + vj) * H_ + vh];
    f32x4 v0 = *(const f32x4*)vg,          v1 = *(const f32x4*)(vg + H_);
    f32x4 v2 = *(const f32x4*)(vg + 2*H_), v3 = *(const f32x4*)(vg + 3*H_);
    bf16x8 x0, x1;
    #pragma unroll
    for (int j = 0; j < 4; ++j) {
      x0[j] = (__bf16)k0[j]; x0[4 + j] = (__bf16)k1[j];
      x1[j] = (__bf16)k2[j]; x1[4 + j] = (__bf16)k3[j];
    }
    *(bf16x8*)&ks[krow * KS + khq] = x0;
    *(bf16x8*)&ks[krow * KS + khq + 8] = x1;
    #pragma unroll
    for (int e = 0; e < 4; ++e) {
      bf16x4 y = {(__bf16)v0[e], (__bf16)v1[e], (__bf16)v2[e], (__bf16)v3[e]};
      *(bf16x4*)&vt[(vh + e) * KS + vj] = y;
    }
  }
  {  // QPE chunk 0 -> ppos slot 0 (B-frags gathered straight from fp32 PE)
    const f32x4 z = {0.f, 0.f, 0.f, 0.f};
    #pragma unroll
    for (int nt = 0; nt < 2; ++nt) {
      bf16x8 b0, b1;
      #pragma unroll
      for (int j = 0; j < 8; ++j) {
        b0[j] = (__bf16)peg[(size_t)j * L_ + 16 * nt];
        b1[j] = (__bf16)peg[(size_t)(32 + j) * L_ + 16 * nt];
      }
      const int colb = (32 * c + 16 * nt + nid) ^ swz;
      #pragma unroll
      for (int it = 0; it < 2; ++it) {
        f32x4 pp = MFMA16(aq[it][0], b0, z);
        pp = MFMA16(aq[it][1], b1, pp);
        #pragma unroll
        for (int r = 0; r < 4; ++r)
          ppos[(32 * a + 16 * it + 4 * qid + r) * PPS + colb] = (__bf16)pp[r];
      }
    }
  }
  __syncthreads();

  // ---------------- main loop: 2 barriers per tile ----------------
  for (int t = 0; t < NT; ++t) {
    // register prefetch of K/V tile t+1 (consumed after barrier A)
    f32x4 kr[4], vr[4];
    if (t < 16) {
      const int j1 = m0 + KT * (t + 1);
      const float* kg = &K[((size_t)b * KL_ + j1 + krow) * H_ + khq];
      kr[0] = *(const f32x4*)kg;       kr[1] = *(const f32x4*)(kg + 4);
      kr[2] = *(const f32x4*)(kg + 8); kr[3] = *(const f32x4*)(kg + 12);
      const float* vg = &V[((size_t)b * KL_ + j1 + vj) * H_ + vh];
      #pragma unroll
      for (int e = 0; e < 4; ++e) vr[e] = *(const f32x4*)(vg + e * H_);
    }
    // prefetch PE B-frags for chunk t+1 (L2-resident strided gather)
    bf16x8 pf[2][2];
    const int ch = t + 1;
    if (t < 15) {
      const float* pc = peg + ch * 64;
      #pragma unroll
      for (int nt = 0; nt < 2; ++nt) {
        #pragma unroll
        for (int j = 0; j < 8; ++j) {
          pf[nt][0][j] = (__bf16)pc[(size_t)j * L_ + 16 * nt];
          pf[nt][1][j] = (__bf16)pc[(size_t)(32 + j) * L_ + 16 * nt];
        }
      }
    }

    const f32x4 z = {0.f, 0.f, 0.f, 0.f};

    // ---- QK^T (2 i-tiles x 2 n-tiles) ----
    f32x4 s[2][2];
    #pragma unroll
    for (int nt = 0; nt < 2; ++nt) {
      const __bf16* kb = &ks[(32 * c + 16 * nt + nid) * KS];
      const bf16x8 b0 = *(const bf16x8*)&kb[8 * qid];
      const bf16x8 b1 = *(const bf16x8*)&kb[32 + 8 * qid];
      #pragma unroll
      for (int it = 0; it < 2; ++it) {
        s[it][nt] = MFMA16(aq[it][0], b0, z);
        s[it][nt] = MFMA16(aq[it][1], b1, s[it][nt]);
      }
    }

    // ---- QPE chunk t+1 -> ppos slot (t+1)%3 (readers use slots (t+2)%3,(t)%3) ----
    if (t < 15) {
      const int sb = 64 * ((t + 1) % 3);
      #pragma unroll
      for (int nt = 0; nt < 2; ++nt) {
        const int colb = sb + ((32 * c + 16 * nt + nid) ^ swz);
        #pragma unroll
        for (int it = 0; it < 2; ++it) {
          f32x4 pp = MFMA16(aq[it][0], pf[nt][0], z);
          pp = MFMA16(aq[it][1], pf[nt][1], pp);
          #pragma unroll
          for (int r = 0; r < 4; ++r)
            ppos[(32 * a + 16 * it + 4 * qid + r) * PPS + colb] = (__bf16)pp[r];
        }
      }
    }

    // ---- softmax: p = exp2(s_cont + pe), pre-scaled; store P; accumulate row sums ----
    const bool edge = (t == 0) || (t == 16);
    const int bc = 64 * (t % 3);            // slot base for chunk t   (delta >= 0)
    const int bp = 64 * ((t + 2) % 3);      // slot base for chunk t-1 (delta < 0)
    #pragma unroll
    for (int it = 0; it < 2; ++it) {
      #pragma unroll
      for (int r = 0; r < 4; ++r) {
        const int il = 32 * a + 16 * it + 4 * qid + r;
        const int rb = il * PPS;
        #pragma unroll
        for (int nt = 0; nt < 2; ++nt) {
          const int delta = 32 * c + 16 * nt + nid - il;   // l - 64t
          const int l = KT * t + delta;
          float p;
          if (!edge || (unsigned)l < 1024u) {
            const int col = (delta < 0 ? bp : bc) + ((delta & 63) ^ swz);
            const float pe = (float)ppos[rb + col];
            p = exp2f(s[it][nt][r] + pe);
          } else {
            p = 0.f;
          }
          lpart[it][r] += p;
          ps[(16 * it + 4 * qid + r) * PSS + 16 * nt + nid] = (__bf16)p;
        }
      }
    }

    // ---- PV (wave-private ps round-trip; per-wave DS ops are in-order) ----
    #pragma unroll
    for (int it = 0; it < 2; ++it) {
      const bf16x8 ap = *(const bf16x8*)&ps[(16 * it + nid) * PSS + 8 * qid];
      #pragma unroll
      for (int ht = 0; ht < 4; ++ht) {
        o[it][ht] = MFMA16(ap, *(const bf16x8*)&vt[(16 * ht + nid) * KS + 32 * c + 8 * qid],
                           o[it][ht]);
      }
    }

    __syncthreads();                   // A: all compute-phase LDS reads done

    // ---- write prefetched tile t+1 into the (single) K/V buffers ----
    if (t < 16) {
      bf16x8 x0, x1;
      #pragma unroll
      for (int j = 0; j < 4; ++j) {
        x0[j] = (__bf16)kr[0][j]; x0[4 + j] = (__bf16)kr[1][j];
        x1[j] = (__bf16)kr[2][j]; x1[4 + j] = (__bf16)kr[3][j];
      }
      *(bf16x8*)&ks[krow * KS + khq] = x0;
      *(bf16x8*)&ks[krow * KS + khq + 8] = x1;
      #pragma unroll
      for (int e = 0; e < 4; ++e) {
        bf16x4 y = {(__bf16)vr[0][e], (__bf16)vr[1][e], (__bf16)vr[2][e], (__bf16)vr[3][e]};
        *(bf16x4*)&vt[(vh + e) * KS + vj] = y;
      }
    }
    __syncthreads();                   // B: staging visible
  }

  // ---------------- epilogue: merge c-halves, normalize, store ----------------
  float* lsum = (float*)(smem + OFF_LSUM);
  float* obuf = (float*)(smem + OFF_OBUF);

  #pragma unroll
  for (int it = 0; it < 2; ++it) {
    #pragma unroll
    for (int r = 0; r < 4; ++r) {
      float v = lpart[it][r];
      v += __shfl_xor(v, 1); v += __shfl_xor(v, 2);
      v += __shfl_xor(v, 4); v += __shfl_xor(v, 8);
      lpart[it][r] = v;
    }
  }
  if (nid == 0) {
    #pragma unroll
    for (int it = 0; it < 2; ++it)
      #pragma unroll
      for (int r = 0; r < 4; ++r)
        lsum[c * 64 + 32 * a + 16 * it + 4 * qid + r] = lpart[it][r];
  }
  if (c == 1) {
    #pragma unroll
    for (int it = 0; it < 2; ++it)
      #pragma unroll
      for (int ht = 0; ht < 4; ++ht)
        *(f32x4*)&obuf[(a * 64 + 16 * ht + nid) * OBS + 16 * it + 4 * qid] = o[it][ht];
  }
  __syncthreads();
  if (c == 0) {
    float inv[2][4];
    #pragma unroll
    for (int it = 0; it < 2; ++it)
      #pragma unroll
      for (int r = 0; r < 4; ++r) {
        const int row = 32 * a + 16 * it + 4 * qid + r;
        inv[it][r] = 1.f / (lsum[row] + lsum[64 + row]);
      }
    #pragma unroll
    for (int it = 0; it < 2; ++it) {
      #pragma unroll
      for (int ht = 0; ht < 4; ++ht) {
        f32x4 oo = o[it][ht] +
                   *(const f32x4*)&obuf[(a * 64 + 16 * ht + nid) * OBS + 16 * it + 4 * qid];
        #pragma unroll
        for (int r = 0; r < 4; ++r) {
          const int row = 32 * a + 16 * it + 4 * qid + r;
          O[((size_t)b * M_ + m0 + row) * H_ + 16 * ht + nid] = oo[r] * inv[it][r];
        }
      }
    }
  }
}

extern "C" void kernel_launch(void* const* d_in, const int* in_sizes, int n_in,
                              void* d_out, int out_size, void* d_ws, size_t ws_size,
                              hipStream_t stream) {
  const float* Q  = (const float*)d_in[0];   // B x M x H
  const float* K  = (const float*)d_in[1];   // B x (M+L) x H
  const float* V  = (const float*)d_in[2];   // B x (M+L) x H
  const float* PE = (const float*)d_in[3];   // 1 x H x L
  float* O = (float*)d_out;                  // B x M x H

  dim3 grid(B_, M_ / BM);                    // batch on x: XCD-local K/V reuse
  hipLaunchKernelGGL(seqattn_v6, grid, dim3(256), 0, stream, Q, K, V, PE, O);
}

// Round 7
// 225.905 us; speedup vs baseline: 1.3711x; 1.3711x over previous
//
#include <hip/hip_runtime.h>
#include <math.h>

typedef __bf16 bf16x8 __attribute__((ext_vector_type(8)));
typedef __bf16 bf16x4 __attribute__((ext_vector_type(4)));
typedef float  f32x4  __attribute__((ext_vector_type(4)));

// Problem constants
constexpr int B_  = 128;
constexpr int M_  = 512;
constexpr int L_  = 1024;
constexpr int H_  = 64;
constexpr int KL_ = 1536;

// Tiling: 64 query rows x 64 key cols; 4 waves = (2 row-halves a) x (2 col-halves c)
constexpr int BM = 64;
constexpr int KT = 64;
constexpr int NT = 17;               // 17*64 = 1088 covers the 1024-band + 64-row skew
constexpr int KS = 72;               // ks/vt row stride (bf16): 144B -> 2-way max on frag reads
constexpr int PPS = 192;             // ppos row stride (bf16): 3 rolling 64-wide chunks
constexpr int PSS = 40;              // ps row stride (bf16): 80B, 16B-aligned rows

// LDS layout — 53248 B total -> 3 blocks/CU (159744 <= 163840)
constexpr int OFF_KS   = 0;          // ks[64][72] bf16     9216 B (single buffer)
constexpr int OFF_VT   = 9216;       // vt[64][72] bf16     9216 B (V^T, single buffer)
constexpr int OFF_PPOS = 18432;      // ppos[64][192] bf16 24576 B (3 rolling QPE chunks)
constexpr int OFF_PS   = 43008;      // ps[4][32][40] bf16 10240 B (wave-private P)
constexpr int SMEM_BYTES = 53248;
// epilogue overlays (after final barrier):
constexpr int OFF_OBUF = 0;          // [2][64][36] f32 partial O (18432 B, over ks+vt)
constexpr int OFF_LSUM = 18432;      // [2][64] f32 row sums (over ppos, dead by then)
constexpr int OBS = 36;

// exp(x/8) == exp2(x * 0.125*log2(e)); fold into Q so QPE comes out pre-scaled too.
constexpr float QSCALE = 0.18033688011112043f;   // 0.125 * log2(e)

#define MFMA16(A, B, C) __builtin_amdgcn_mfma_f32_16x16x32_bf16((A), (B), (C), 0, 0, 0)

// NOTE: __launch_bounds__ second arg MUST stay 2. Round 6 set it to 3 and the
// tightened register budget spilled the cross-phase prefetch registers to
// scratch (WRITE_SIZE 16->87 MB, dur 127->219 us). 3 blocks/CU residency comes
// from LDS (53248 B) + actual VGPR count (~88), not from this annotation.
__global__ __launch_bounds__(256, 2)
void seqattn_v7(const float* __restrict__ Q, const float* __restrict__ K,
                const float* __restrict__ V, const float* __restrict__ PE,
                float* __restrict__ O) {
  __shared__ alignas(16) char smem[SMEM_BYTES];
  __bf16* ks   = (__bf16*)(smem + OFF_KS);
  __bf16* vt   = (__bf16*)(smem + OFF_VT);
  __bf16* ppos = (__bf16*)(smem + OFF_PPOS);

  const int tid  = threadIdx.x;
  const int w    = tid >> 6;
  const int lane = tid & 63;
  const int nid  = lane & 15;
  const int qid  = lane >> 4;
  const int a    = w >> 1;            // rows 32a..32a+31
  const int c    = w & 1;             // tile cols 32c..32c+31
  const int b    = blockIdx.x;        // batch on x -> same-batch blocks share an XCD
  const int m0   = blockIdx.y * BM;
  const int swz  = qid << 4;          // in-slot bank swizzle (slot width 64, xor bits 4..5)

  __bf16* ps = (__bf16*)(smem + OFF_PS) + w * 32 * PSS;

  // ---- Q A-fragments, pre-scaled by 0.125*log2(e) ----
  bf16x8 aq[2][2];
  #pragma unroll
  for (int it = 0; it < 2; ++it) {
    const float* qg = &Q[((size_t)b * M_ + m0 + 32 * a + 16 * it + nid) * H_];
    #pragma unroll
    for (int j = 0; j < 8; ++j) {
      aq[it][0][j] = (__bf16)(qg[8 * qid + j] * QSCALE);
      aq[it][1][j] = (__bf16)(qg[32 + 8 * qid + j] * QSCALE);
    }
  }

  f32x4 o[2][4];
  float lpart[2][4];
  #pragma unroll
  for (int it = 0; it < 2; ++it) {
    #pragma unroll
    for (int ht = 0; ht < 4; ++ht) o[it][ht] = (f32x4){0.f, 0.f, 0.f, 0.f};
    #pragma unroll
    for (int r = 0; r < 4; ++r) lpart[it][r] = 0.f;
  }

  const int krow = tid >> 2,  khq = (tid & 3) * 16;   // K staging: 4 thr/row
  const int vj = (tid & 15) * 4, vh = (tid >> 4) * 4; // V staging: 4x4 reg transpose

  // PE B-frag gather base: frag[nt][h][j] = PE[(32h+8qid+j)*L + ch*64+32c+16nt+nid]
  const float* peg = &PE[(size_t)(8 * qid) * L_ + 32 * c + nid];

  // ---------------- prologue: stage tile 0 + QPE chunk 0 (slot 0) ----------------
  {
    const float* kg = &K[((size_t)b * KL_ + m0 + krow) * H_ + khq];
    f32x4 k0 = *(const f32x4*)kg,       k1 = *(const f32x4*)(kg + 4);
    f32x4 k2 = *(const f32x4*)(kg + 8), k3 = *(const f32x4*)(kg + 12);
    const float* vg = &V[((size_t)b * KL_ + m0 + vj) * H_ + vh];
    f32x4 v0 = *(const f32x4*)vg,          v1 = *(const f32x4*)(vg + H_);
    f32x4 v2 = *(const f32x4*)(vg + 2*H_), v3 = *(const f32x4*)(vg + 3*H_);
    bf16x8 x0, x1;
    #pragma unroll
    for (int j = 0; j < 4; ++j) {
      x0[j] = (__bf16)k0[j]; x0[4 + j] = (__bf16)k1[j];
      x1[j] = (__bf16)k2[j]; x1[4 + j] = (__bf16)k3[j];
    }
    *(bf16x8*)&ks[krow * KS + khq] = x0;
    *(bf16x8*)&ks[krow * KS + khq + 8] = x1;
    #pragma unroll
    for (int e = 0; e < 4; ++e) {
      bf16x4 y = {(__bf16)v0[e], (__bf16)v1[e], (__bf16)v2[e], (__bf16)v3[e]};
      *(bf16x4*)&vt[(vh + e) * KS + vj] = y;
    }
  }
  {  // QPE chunk 0 -> ppos slot 0 (B-frags gathered straight from fp32 PE)
    const f32x4 z = {0.f, 0.f, 0.f, 0.f};
    #pragma unroll
    for (int nt = 0; nt < 2; ++nt) {
      bf16x8 b0, b1;
      #pragma unroll
      for (int j = 0; j < 8; ++j) {
        b0[j] = (__bf16)peg[(size_t)j * L_ + 16 * nt];
        b1[j] = (__bf16)peg[(size_t)(32 + j) * L_ + 16 * nt];
      }
      const int colb = (32 * c + 16 * nt + nid) ^ swz;
      #pragma unroll
      for (int it = 0; it < 2; ++it) {
        f32x4 pp = MFMA16(aq[it][0], b0, z);
        pp = MFMA16(aq[it][1], b1, pp);
        #pragma unroll
        for (int r = 0; r < 4; ++r)
          ppos[(32 * a + 16 * it + 4 * qid + r) * PPS + colb] = (__bf16)pp[r];
      }
    }
  }
  __syncthreads();

  // ---------------- main loop: 2 barriers per tile ----------------
  for (int t = 0; t < NT; ++t) {
    // register prefetch of K/V tile t+1 (consumed after barrier A)
    f32x4 kr[4], vr[4];
    if (t < 16) {
      const int j1 = m0 + KT * (t + 1);
      const float* kg = &K[((size_t)b * KL_ + j1 + krow) * H_ + khq];
      kr[0] = *(const f32x4*)kg;       kr[1] = *(const f32x4*)(kg + 4);
      kr[2] = *(const f32x4*)(kg + 8); kr[3] = *(const f32x4*)(kg + 12);
      const float* vg = &V[((size_t)b * KL_ + j1 + vj) * H_ + vh];
      #pragma unroll
      for (int e = 0; e < 4; ++e) vr[e] = *(const f32x4*)(vg + e * H_);
    }
    // prefetch PE B-frags for chunk t+1 (L2-resident strided gather)
    bf16x8 pf[2][2];
    const int ch = t + 1;
    if (t < 15) {
      const float* pc = peg + ch * 64;
      #pragma unroll
      for (int nt = 0; nt < 2; ++nt) {
        #pragma unroll
        for (int j = 0; j < 8; ++j) {
          pf[nt][0][j] = (__bf16)pc[(size_t)j * L_ + 16 * nt];
          pf[nt][1][j] = (__bf16)pc[(size_t)(32 + j) * L_ + 16 * nt];
        }
      }
    }

    const f32x4 z = {0.f, 0.f, 0.f, 0.f};

    // ---- QK^T (2 i-tiles x 2 n-tiles) ----
    f32x4 s[2][2];
    #pragma unroll
    for (int nt = 0; nt < 2; ++nt) {
      const __bf16* kb = &ks[(32 * c + 16 * nt + nid) * KS];
      const bf16x8 b0 = *(const bf16x8*)&kb[8 * qid];
      const bf16x8 b1 = *(const bf16x8*)&kb[32 + 8 * qid];
      #pragma unroll
      for (int it = 0; it < 2; ++it) {
        s[it][nt] = MFMA16(aq[it][0], b0, z);
        s[it][nt] = MFMA16(aq[it][1], b1, s[it][nt]);
      }
    }

    // ---- QPE chunk t+1 -> ppos slot (t+1)%3 (readers use slots t%3, (t+2)%3) ----
    if (t < 15) {
      const int sb = 64 * ((t + 1) % 3);
      #pragma unroll
      for (int nt = 0; nt < 2; ++nt) {
        const int colb = sb + ((32 * c + 16 * nt + nid) ^ swz);
        #pragma unroll
        for (int it = 0; it < 2; ++it) {
          f32x4 pp = MFMA16(aq[it][0], pf[nt][0], z);
          pp = MFMA16(aq[it][1], pf[nt][1], pp);
          #pragma unroll
          for (int r = 0; r < 4; ++r)
            ppos[(32 * a + 16 * it + 4 * qid + r) * PPS + colb] = (__bf16)pp[r];
        }
      }
    }

    // ---- softmax: p = exp2(s_cont + pe), pre-scaled; store P; accumulate row sums ----
    const bool edge = (t == 0) || (t == 16);
    const int bc = 64 * (t % 3);            // slot base for chunk t   (delta >= 0)
    const int bp = 64 * ((t + 2) % 3);      // slot base for chunk t-1 (delta < 0)
    #pragma unroll
    for (int it = 0; it < 2; ++it) {
      #pragma unroll
      for (int r = 0; r < 4; ++r) {
        const int il = 32 * a + 16 * it + 4 * qid + r;
        const int rb = il * PPS;
        #pragma unroll
        for (int nt = 0; nt < 2; ++nt) {
          const int delta = 32 * c + 16 * nt + nid - il;   // l - 64t
          const int l = KT * t + delta;
          float p;
          if (!edge || (unsigned)l < 1024u) {
            const int col = (delta < 0 ? bp : bc) + ((delta & 63) ^ swz);
            const float pe = (float)ppos[rb + col];
            p = exp2f(s[it][nt][r] + pe);
          } else {
            p = 0.f;
          }
          lpart[it][r] += p;
          ps[(16 * it + 4 * qid + r) * PSS + 16 * nt + nid] = (__bf16)p;
        }
      }
    }

    // ---- PV (wave-private ps round-trip; per-wave DS ops are in-order) ----
    #pragma unroll
    for (int it = 0; it < 2; ++it) {
      const bf16x8 ap = *(const bf16x8*)&ps[(16 * it + nid) * PSS + 8 * qid];
      #pragma unroll
      for (int ht = 0; ht < 4; ++ht) {
        o[it][ht] = MFMA16(ap, *(const bf16x8*)&vt[(16 * ht + nid) * KS + 32 * c + 8 * qid],
                           o[it][ht]);
      }
    }

    __syncthreads();                   // A: all compute-phase LDS reads done

    // ---- write prefetched tile t+1 into the (single) K/V buffers ----
    if (t < 16) {
      bf16x8 x0, x1;
      #pragma unroll
      for (int j = 0; j < 4; ++j) {
        x0[j] = (__bf16)kr[0][j]; x0[4 + j] = (__bf16)kr[1][j];
        x1[j] = (__bf16)kr[2][j]; x1[4 + j] = (__bf16)kr[3][j];
      }
      *(bf16x8*)&ks[krow * KS + khq] = x0;
      *(bf16x8*)&ks[krow * KS + khq + 8] = x1;
      #pragma unroll
      for (int e = 0; e < 4; ++e) {
        bf16x4 y = {(__bf16)vr[0][e], (__bf16)vr[1][e], (__bf16)vr[2][e], (__bf16)vr[3][e]};
        *(bf16x4*)&vt[(vh + e) * KS + vj] = y;
      }
    }
    __syncthreads();                   // B: staging visible
  }

  // ---------------- epilogue: merge c-halves, normalize, store ----------------
  float* lsum = (float*)(smem + OFF_LSUM);
  float* obuf = (float*)(smem + OFF_OBUF);

  #pragma unroll
  for (int it = 0; it < 2; ++it) {
    #pragma unroll
    for (int r = 0; r < 4; ++r) {
      float v = lpart[it][r];
      v += __shfl_xor(v, 1); v += __shfl_xor(v, 2);
      v += __shfl_xor(v, 4); v += __shfl_xor(v, 8);
      lpart[it][r] = v;
    }
  }
  if (nid == 0) {
    #pragma unroll
    for (int it = 0; it < 2; ++it)
      #pragma unroll
      for (int r = 0; r < 4; ++r)
        lsum[c * 64 + 32 * a + 16 * it + 4 * qid + r] = lpart[it][r];
  }
  if (c == 1) {
    #pragma unroll
    for (int it = 0; it < 2; ++it)
      #pragma unroll
      for (int ht = 0; ht < 4; ++ht)
        *(f32x4*)&obuf[(a * 64 + 16 * ht + nid) * OBS + 16 * it + 4 * qid] = o[it][ht];
  }
  __syncthreads();
  if (c == 0) {
    float inv[2][4];
    #pragma unroll
    for (int it = 0; it < 2; ++it)
      #pragma unroll
      for (int r = 0; r < 4; ++r) {
        const int row = 32 * a + 16 * it + 4 * qid + r;
        inv[it][r] = 1.f / (lsum[row] + lsum[64 + row]);
      }
    #pragma unroll
    for (int it = 0; it < 2; ++it) {
      #pragma unroll
      for (int ht = 0; ht < 4; ++ht) {
        f32x4 oo = o[it][ht] +
                   *(const f32x4*)&obuf[(a * 64 + 16 * ht + nid) * OBS + 16 * it + 4 * qid];
        #pragma unroll
        for (int r = 0; r < 4; ++r) {
          const int row = 32 * a + 16 * it + 4 * qid + r;
          O[((size_t)b * M_ + m0 + row) * H_ + 16 * ht + nid] = oo[r] * inv[it][r];
        }
      }
    }
  }
}

extern "C" void kernel_launch(void* const* d_in, const int* in_sizes, int n_in,
                              void* d_out, int out_size, void* d_ws, size_t ws_size,
                              hipStream_t stream) {
  const float* Q  = (const float*)d_in[0];   // B x M x H
  const float* K  = (const float*)d_in[1];   // B x (M+L) x H
  const float* V  = (const float*)d_in[2];   // B x (M+L) x H
  const float* PE = (const float*)d_in[3];   // 1 x H x L
  float* O = (float*)d_out;                  // B x M x H

  dim3 grid(B_, M_ / BM);                    // batch on x: XCD-local K/V reuse
  hipLaunchKernelGGL(seqattn_v7, grid, dim3(256), 0, stream, Q, K, V, PE, O);
}